// Round 9
// baseline (282.371 us; speedup 1.0000x reference)
//
#include <hip/hip_runtime.h>
#include <hip/hip_bf16.h>
#include <stdint.h>
#include <math.h>

// Problem constants: B=4, S=2048, D=1024, H=16, DK=64
static constexpr int kS  = 2048;
static constexpr int kH  = 16;
static constexpr int kDK = 64;
static constexpr int kD  = 1024;
static constexpr int kB  = 4;
static constexpr int kM  = kB * kS;   // 8192 tokens

typedef __bf16 bf16;
typedef __attribute__((ext_vector_type(8))) __bf16 bf16x8;
typedef __attribute__((ext_vector_type(4))) __bf16 bf16x4;
typedef __attribute__((ext_vector_type(4))) float f32x4;

__device__ __forceinline__ void gload_lds16(const bf16* g, bf16* l) {
  __builtin_amdgcn_global_load_lds((__attribute__((address_space(1))) void*)(void*)g,
                                   (__attribute__((address_space(3))) void*)l, 16, 0, 0);
}

// ---------------- fp32 -> bf16 converts ----------------
__global__ void cvt_f32_bf16(const float* __restrict__ in, bf16* __restrict__ out, int n4) {
  int i = blockIdx.x * blockDim.x + threadIdx.x;
  if (i >= n4) return;
  float4 v = reinterpret_cast<const float4*>(in)[i];
  bf16x4 o;
  o[0] = (bf16)v.x; o[1] = (bf16)v.y; o[2] = (bf16)v.z; o[3] = (bf16)v.w;
  reinterpret_cast<bf16x4*>(out)[i] = o;
}

__global__ void cvt_w4(const float* __restrict__ w0, const float* __restrict__ w1,
                       const float* __restrict__ w2, const float* __restrict__ w3,
                       bf16* __restrict__ o0, bf16* __restrict__ o1,
                       bf16* __restrict__ o2, bf16* __restrict__ o3, int n4) {
  int i = blockIdx.x * blockDim.x + threadIdx.x;
  if (i >= n4) return;
  const int sel = blockIdx.y;
  const float* in = (sel == 0) ? w0 : (sel == 1) ? w1 : (sel == 2) ? w2 : w3;
  bf16* out      = (sel == 0) ? o0 : (sel == 1) ? o1 : (sel == 2) ? o2 : o3;
  float4 v = reinterpret_cast<const float4*>(in)[i];
  bf16x4 o;
  o[0] = (bf16)v.x; o[1] = (bf16)v.y; o[2] = (bf16)v.z; o[3] = (bf16)v.w;
  reinterpret_cast<bf16x4*>(out)[i] = o;
}

// ---------------- QKV GEMM, 256x256 tile, BK=64 (T2+T4+T5 structure) ----------------
// 8 waves (2Mx4N), 512 threads, 128KB LDS dbuf. T2: LDS linear dest +
// inverse-swizzled global source (col_block ^= row&7) + swizzled ds_read ->
// frag reads are 2 lanes/bank (free). T4: STAGE(t+1) issued before compute(t),
// counted s_waitcnt vmcnt(8) + raw s_barrier (loads stay in flight across the
// barrier). Closing barrier per K-tile guards buffer reuse.
__global__ __launch_bounds__(512, 2) void gemm_qkv256(const bf16* __restrict__ A,
                                                      const bf16* __restrict__ wq,
                                                      const bf16* __restrict__ wk,
                                                      const bf16* __restrict__ wv,
                                                      bf16* __restrict__ Qb,
                                                      bf16* __restrict__ Kb,
                                                      bf16* __restrict__ Vb, int K) {
  __shared__ __align__(16) bf16 LA[2][256 * 64];
  __shared__ __align__(16) bf16 LB[2][256 * 64];

  const int by  = blockIdx.y;
  const int sel = by >> 2;
  const bf16* W = (sel == 0) ? wq : (sel == 1) ? wk : wv;
  bf16* dst     = (sel == 0) ? Qb : (sel == 1) ? Kb : Vb;
  const int brow = blockIdx.x * 256;
  const int bcol = (by & 3) * 256;

  const int tid = threadIdx.x;
  const int l   = tid & 63;
  const int w   = tid >> 6;             // 0..7
  const int wm  = w >> 2;               // 0..1 -> 128 rows
  const int wn  = w & 3;                // 0..3 -> 64 cols
  const int fr  = l & 15;
  const int fkg = l >> 4;               // 0..3

  const int srow = tid >> 3;            // 0..63
  const int scb  = tid & 7;             // source col-block (pre-swizzle)

  f32x4 acc[8][4] = {};

  const int nk = K >> 6;                // BK=64 steps (16)

  auto STAGE = [&](int buf, int kt) {
    const int k0 = kt << 6;
#pragma unroll
    for (int li = 0; li < 4; ++li) {
      const int row = li * 64 + srow;
      const int cb  = scb ^ (row & 7);  // inverse swizzle on SOURCE
      gload_lds16(A + (size_t)(brow + row) * K + k0 + cb * 8,
                  &LA[buf][li * 4096 + srow * 64 + scb * 8]);
    }
#pragma unroll
    for (int li = 0; li < 4; ++li) {
      const int row = li * 64 + srow;
      const int cb  = scb ^ (row & 7);
      gload_lds16(W + (size_t)(bcol + row) * K + k0 + cb * 8,
                  &LB[buf][li * 4096 + srow * 64 + scb * 8]);
    }
  };

  STAGE(0, 0);

  int cur = 0;
  for (int kt = 0; kt < nk; ++kt) {
    if (kt + 1 < nk) {
      STAGE(cur ^ 1, kt + 1);                       // 8 loads stay in flight
      asm volatile("s_waitcnt vmcnt(8)" ::: "memory");   // tile kt resident
    } else {
      asm volatile("s_waitcnt vmcnt(0)" ::: "memory");
    }
    __builtin_amdgcn_s_barrier();
    __builtin_amdgcn_sched_barrier(0);

#pragma unroll
    for (int kc = 0; kc < 2; ++kc) {
      bf16x8 af[8], bfr[4];
#pragma unroll
      for (int m = 0; m < 8; ++m) {
        const int row = wm * 128 + m * 16 + fr;
        af[m] = *(const bf16x8*)&LA[cur][row * 64 + (((kc * 4 + fkg) ^ (fr & 7)) * 8)];
      }
#pragma unroll
      for (int n = 0; n < 4; ++n) {
        const int row = wn * 64 + n * 16 + fr;
        bfr[n] = *(const bf16x8*)&LB[cur][row * 64 + (((kc * 4 + fkg) ^ (fr & 7)) * 8)];
      }
      __builtin_amdgcn_s_setprio(1);
#pragma unroll
      for (int m = 0; m < 8; ++m)
#pragma unroll
        for (int n = 0; n < 4; ++n)
          acc[m][n] = __builtin_amdgcn_mfma_f32_16x16x32_bf16(af[m], bfr[n], acc[m][n], 0, 0, 0);
      __builtin_amdgcn_s_setprio(0);
    }

    __builtin_amdgcn_s_barrier();   // all reads of cur done before it is overwritten
    cur ^= 1;
  }

  // epilogue: bf16 permuted [B][H][S][DK]
  const int frow = fkg * 4;
#pragma unroll
  for (int m = 0; m < 8; ++m) {
#pragma unroll
    for (int n = 0; n < 4; ++n) {
      const int col = bcol + wn * 64 + n * 16 + fr;
      const int h = col >> 6, dk = col & 63;
#pragma unroll
      for (int r = 0; r < 4; ++r) {
        const int row = brow + wm * 128 + m * 16 + frow + r;
        const int b = row >> 11, s = row & (kS - 1);
        dst[((((size_t)b * kH + h) * kS + s) << 6) + dk] = (bf16)acc[m][n][r];
      }
    }
  }
}

// ---------------- WO GEMM: 128x128 tile, BK=32, depth-2 counted vmcnt ----------------
template<int BM>
__device__ __forceinline__ void gemm_body(const bf16* __restrict__ A,
                                          const bf16* __restrict__ W,
                                          void* __restrict__ dst,
                                          int K, int mode, int brow, int bcol) {
  constexpr int MF  = BM / 32;
  constexpr int ACH = BM / 64;

  __shared__ __align__(16) bf16 As[3][BM * 32];
  __shared__ __align__(16) bf16 Bs[3][128 * 32];

  const int tid = threadIdx.x;
  const int l   = tid & 63;
  const int w   = tid >> 6;
  const int wr = (w >> 1) * (BM / 2);
  const int wc = (w & 1) * 64;

  f32x4 acc[MF][4] = {};

  const int lrow = l >> 2;
  const int lcol = (l & 3) * 8;
  const int fr  = l & 15;
  const int fk  = (l >> 4) * 8;

  const int nk = K >> 5;

  auto STAGE = [&](int buf, int kt) {
    const int k0 = kt << 5;
#pragma unroll
    for (int c2 = 0; c2 < ACH; ++c2) {
      const int c = w * ACH + c2;
      gload_lds16(A + (size_t)(brow + c * 16 + lrow) * K + k0 + lcol, &As[buf][c * 512]);
    }
#pragma unroll
    for (int c2 = 0; c2 < 2; ++c2) {
      const int c = w * 2 + c2;
      gload_lds16(W + (size_t)(bcol + c * 16 + lrow) * K + k0 + lcol, &Bs[buf][c * 512]);
    }
  };

  STAGE(0, 0);
  STAGE(1, 1);

  int cur = 0;
  for (int kt = 0; kt < nk; ++kt) {
    if (kt + 1 < nk) { asm volatile("s_waitcnt vmcnt(4)" ::: "memory"); }
    else             { asm volatile("s_waitcnt vmcnt(0)" ::: "memory"); }
    __builtin_amdgcn_s_barrier();
    __builtin_amdgcn_sched_barrier(0);

    if (kt + 2 < nk) {
      int s2 = cur + 2; if (s2 >= 3) s2 -= 3;
      STAGE(s2, kt + 2);
    }

    bf16x8 af[MF], bfm[4];
#pragma unroll
    for (int m = 0; m < MF; ++m) af[m]  = *(const bf16x8*)&As[cur][(wr + m * 16 + fr) * 32 + fk];
#pragma unroll
    for (int n = 0; n < 4; ++n)  bfm[n] = *(const bf16x8*)&Bs[cur][(wc + n * 16 + fr) * 32 + fk];
#pragma unroll
    for (int m = 0; m < MF; ++m)
#pragma unroll
      for (int n = 0; n < 4; ++n)
        acc[m][n] = __builtin_amdgcn_mfma_f32_16x16x32_bf16(af[m], bfm[n], acc[m][n], 0, 0, 0);

    cur = (cur + 1 == 3) ? 0 : cur + 1;
  }

  const int frow = (l >> 4) * 4;
  if (mode == 0) {
    bf16* out = (bf16*)dst;
#pragma unroll
    for (int m = 0; m < MF; ++m) {
#pragma unroll
      for (int n = 0; n < 4; ++n) {
        const int col = bcol + wc + n * 16 + fr;
        const int h = col >> 6, dk = col & 63;
#pragma unroll
        for (int r = 0; r < 4; ++r) {
          const int row = brow + wr + m * 16 + frow + r;
          const int b = row >> 11, s = row & (kS - 1);
          out[((((size_t)b * kH + h) * kS + s) << 6) + dk] = (bf16)acc[m][n][r];
        }
      }
    }
  } else {
    float* out = (float*)dst;
#pragma unroll
    for (int m = 0; m < MF; ++m) {
#pragma unroll
      for (int n = 0; n < 4; ++n) {
        const int col = bcol + wc + n * 16 + fr;
#pragma unroll
        for (int r = 0; r < 4; ++r) {
          const int row = brow + wr + m * 16 + frow + r;
          out[(size_t)row * kD + col] = acc[m][n][r];
        }
      }
    }
  }
}

template<int BM>
__global__ __launch_bounds__(256) void gemm_k(const bf16* __restrict__ A,
                                              const bf16* __restrict__ W,
                                              void* __restrict__ dst, int K, int mode) {
  gemm_body<BM>(A, W, dst, K, mode, blockIdx.x * BM, blockIdx.y * 128);
}

// ---------------- RoPE, in-place; Q pre-scaled by 1/8*log2e ----------------
__global__ void rope_kernel(bf16* __restrict__ Q, bf16* __restrict__ Kb,
                            const int* __restrict__ pos, int np) {
  int idx = blockIdx.x * blockDim.x + threadIdx.x;
  if (idx >= 2 * np) return;
  const bool isQ = (idx < np);
  bf16* T = isQ ? Q : Kb;
  int id = isQ ? idx : idx - np;
  const int i = id & 31;
  const int s = (id >> 5) & (kS - 1);
  const float p = (float)pos[s];
  const float freq = __expf(-0.2878231366242557f * (float)i);
  const float frev = p * freq * 0.15915494309189535f;   // radians -> revolutions
  const float r = frev - floorf(frev);
  const float sn = __builtin_amdgcn_sinf(r);
  const float cs = __builtin_amdgcn_cosf(r);
  const float sc = isQ ? (0.125f * 1.4426950408889634f) : 1.0f;
  const size_t off = (size_t)id * 2;
  const float e = (float)T[off], o = (float)T[off + 1];
  T[off]     = (bf16)((e * cs - o * sn) * sc);
  T[off + 1] = (bf16)((o * cs + e * sn) * sc);
}

// ---------------- causal flash attention v4 (unchanged) ----------------
__global__ __launch_bounds__(256) void attn_fwd(const bf16* __restrict__ Q,
                                                const bf16* __restrict__ Kb,
                                                const bf16* __restrict__ Vb,
                                                bf16* __restrict__ O) {
  const int bh = blockIdx.x;
  const int qt = (int)gridDim.y - 1 - (int)blockIdx.y;   // heavy blocks first
  const int tid = threadIdx.x;
  const int l = tid & 63;
  const int w = tid >> 6;

  __shared__ __align__(16) bf16 Ks[64 * 64];   // [kv][dk], swizzled
  __shared__ __align__(16) bf16 Vt[64 * 64];   // [dk][kv], swizzled
  __shared__ __align__(16) bf16 Pl[4][16 * 64];// per-wave [q][kv], swizzled

  const int q0 = qt * 64 + w * 16;
  const int fr  = l & 15;
  const int fkg = l >> 4;                      // 0..3
  const int fkg4 = fkg << 2;
  const size_t base = (size_t)bh * kS * kDK;

  bf16x8 aq[2];
#pragma unroll
  for (int kc = 0; kc < 2; ++kc)
    aq[kc] = *(const bf16x8*)&Q[base + (size_t)(q0 + fr) * kDK + kc * 32 + fkg * 8];

  f32x4 ao[4] = {};
  float m_r = -1e30f, l_r = 0.f;

  const int nt = qt + 1;

  const int krow = tid >> 3;
  const int kcol = (tid & 7) * 8;
  const int dk0  = w * 16;

  bf16x8 kreg0, kreg1, vreg0, vreg1;
  {
    const size_t kb0 = base + (size_t)krow * kDK + kcol;
    kreg0 = *(const bf16x8*)&Kb[kb0];
    kreg1 = *(const bf16x8*)&Kb[kb0 + 32 * kDK];
    const size_t vb0 = base + (size_t)l * kDK + dk0;
    vreg0 = *(const bf16x8*)&Vb[vb0];
    vreg1 = *(const bf16x8*)&Vb[vb0 + 8];
  }

  for (int j = 0; j < nt; ++j) {
    {
      const int r0 = krow, r1 = krow + 32;
      *(bf16x8*)&Ks[r0 * 64 + (kcol ^ ((r0 & 7) << 3))] = kreg0;
      *(bf16x8*)&Ks[r1 * 64 + (kcol ^ ((r1 & 7) << 3))] = kreg1;
#pragma unroll
      for (int e = 0; e < 8; ++e) {
        const int d0 = dk0 + e, d1 = dk0 + 8 + e;
        Vt[d0 * 64 + (l ^ ((d0 & 7) << 3))] = vreg0[e];
        Vt[d1 * 64 + (l ^ ((d1 & 7) << 3))] = vreg1[e];
      }
    }
    __syncthreads();

    if (j + 1 < nt) {
      const size_t kb0 = base + (size_t)((j + 1) * 64 + krow) * kDK + kcol;
      kreg0 = *(const bf16x8*)&Kb[kb0];
      kreg1 = *(const bf16x8*)&Kb[kb0 + 32 * kDK];
      const size_t vb0 = base + (size_t)((j + 1) * 64 + l) * kDK + dk0;
      vreg0 = *(const bf16x8*)&Vb[vb0];
      vreg1 = *(const bf16x8*)&Vb[vb0 + 8];
    }

    const bool diag = (j == nt - 1);

    f32x4 sc[4] = {};
#pragma unroll
    for (int nf = 0; nf < 4; ++nf) {
      if (!diag || nf <= w) {
#pragma unroll
        for (int kc = 0; kc < 2; ++kc) {
          const int row = nf * 16 + fr;
          bf16x8 bk = *(const bf16x8*)&Ks[row * 64 + ((kc * 32 + fkg * 8) ^ ((row & 7) << 3))];
          sc[nf] = __builtin_amdgcn_mfma_f32_16x16x32_bf16(bk, aq[kc], sc[nf], 0, 0, 0);
        }
      }
    }

    const int qloc = w * 16 + fr;
    float p[4][4];
    float mx = -INFINITY;
#pragma unroll
    for (int nf = 0; nf < 4; ++nf)
#pragma unroll
      for (int r = 0; r < 4; ++r) {
        float s = sc[nf][r];
        if (diag && (nf * 16 + fkg4 + r) > qloc) s = -INFINITY;
        p[nf][r] = s;
        mx = fmaxf(mx, s);
      }
    mx = fmaxf(mx, __shfl_xor(mx, 16));
    mx = fmaxf(mx, __shfl_xor(mx, 32));

    if (__any(mx > m_r + 11.5f)) {
      const float mnew = fmaxf(m_r, mx);
      const float sf = __builtin_amdgcn_exp2f(m_r - mnew);
      l_r *= sf;
      m_r = mnew;
#pragma unroll
      for (int r = 0; r < 4; ++r) {
        const float sfq = __shfl(sf, (l & 48) + fkg4 + r);
#pragma unroll
        for (int n = 0; n < 4; ++n) ao[n][r] *= sfq;
      }
    }

    float rs = 0.f;
#pragma unroll
    for (int nf = 0; nf < 4; ++nf)
#pragma unroll
      for (int r = 0; r < 4; ++r) {
        p[nf][r] = __builtin_amdgcn_exp2f(p[nf][r] - m_r);
        rs += p[nf][r];
      }
    rs += __shfl_xor(rs, 16);
    rs += __shfl_xor(rs, 32);
    l_r += rs;

#pragma unroll
    for (int nf = 0; nf < 4; ++nf) {
      bf16x4 p4;
#pragma unroll
      for (int r = 0; r < 4; ++r) p4[r] = (bf16)p[nf][r];
      *(bf16x4*)&Pl[w][fr * 64 + ((nf * 16 + fkg4) ^ ((fr & 7) << 3))] = p4;
    }
    bf16x8 pa[2];
#pragma unroll
    for (int kc2 = 0; kc2 < 2; ++kc2)
      pa[kc2] = *(const bf16x8*)&Pl[w][fr * 64 + ((kc2 * 32 + fkg * 8) ^ ((fr & 7) << 3))];

#pragma unroll
    for (int kc2 = 0; kc2 < 2; ++kc2) {
      if (kc2 == 0 || !diag || w >= 2) {
#pragma unroll
        for (int n = 0; n < 4; ++n) {
          const int row = n * 16 + fr;
          bf16x8 bv = *(const bf16x8*)&Vt[row * 64 + ((kc2 * 32 + fkg * 8) ^ ((row & 7) << 3))];
          ao[n] = __builtin_amdgcn_mfma_f32_16x16x32_bf16(pa[kc2], bv, ao[n], 0, 0, 0);
        }
      }
    }
    __syncthreads();
  }

  const int b = bh >> 4, h = bh & 15;
  float lq[4];
#pragma unroll
  for (int r = 0; r < 4; ++r) lq[r] = __shfl(l_r, (l & 48) + fkg4 + r);
#pragma unroll
  for (int n = 0; n < 4; ++n)
#pragma unroll
    for (int r = 0; r < 4; ++r) {
      const int qg = q0 + fkg4 + r;
      const float ov = ao[n][r] / lq[r];
      O[((size_t)(b * kS + qg) << 10) + h * 64 + n * 16 + fr] = (bf16)ov;
    }
}

// ---------------- launch ----------------
extern "C" void kernel_launch(void* const* d_in, const int* in_sizes, int n_in,
                              void* d_out, int out_size, void* d_ws, size_t ws_size,
                              hipStream_t stream) {
  const float* x  = (const float*)d_in[0];
  const float* wq = (const float*)d_in[1];
  const float* wk = (const float*)d_in[2];
  const float* wv = (const float*)d_in[3];
  const float* wo = (const float*)d_in[4];
  const int* pos  = (const int*)d_in[5];

  bf16* xb  = (bf16*)d_ws;                          // [8192][1024]
  bf16* wqb = xb  + (size_t)kM * kD;
  bf16* wkb = wqb + (size_t)kD * kD;
  bf16* wvb = wkb + (size_t)kD * kD;
  bf16* wob = wvb + (size_t)kD * kD;
  bf16* Qb  = wob + (size_t)kD * kD;                // [64][2048][64]
  bf16* Kbf = Qb  + (size_t)64 * kS * kDK;
  bf16* Vbf = Kbf + (size_t)64 * kS * kDK;
  bf16* Ob  = Vbf + (size_t)64 * kS * kDK;          // [8192][1024]

  {
    int n4 = kM * kD / 4;
    cvt_f32_bf16<<<(n4 + 255) / 256, 256, 0, stream>>>(x, xb, n4);
    n4 = kD * kD / 4;
    cvt_w4<<<dim3((n4 + 255) / 256, 4), 256, 0, stream>>>(wq, wk, wv, wo, wqb, wkb, wvb, wob, n4);
  }

  // fused QKV: 256x256 tiles, BK=64, counted-vmcnt pipeline -> grid (32, 12)
  gemm_qkv256<<<dim3(kM / 256, 12), 512, 0, stream>>>(xb, wqb, wkb, wvb, Qb, Kbf, Vbf, kD);

  const int np = 64 * kS * 32;
  rope_kernel<<<(2 * np) / 256, 256, 0, stream>>>(Qb, Kbf, pos, np);

  dim3 ga(64, kS / 64);          // (bh, qtile)
  attn_fwd<<<ga, 256, 0, stream>>>(Qb, Kbf, Vbf, Ob);

  // WO: 128x128 tiles -> grid (64, 8)
  gemm_k<128><<<dim3(kM / 128, kD / 128), 256, 0, stream>>>(Ob, wob, d_out, kD, 1);
}